// Round 6
// baseline (1492.218 us; speedup 1.0000x reference)
//
#include <hip/hip_runtime.h>
#include <math.h>

// VQ nearest-code: out[t] = codebook[argmax_k(e_sq[k] - 2*x_t.c_k)]  (argmax quirk preserved)
// R6: two-pass. prep: f32 -> split-f16 (hi/lo) of cb & x + e_sq into d_ws.
//     main: MFMA GEMM (3-product hh+hl+lh) with global_load_lds staging, dbuf LDS,
//           2-phase template (STAGE top, vmcnt(0)+barrier bottom). Fallback if ws too small.

#define NTOK   32768
#define NCODE  8192
#define KD     512
#define BT     64      // tokens per block
#define BC     256     // codes per tile
#define BK     32      // k per step
#define NTILE  (NCODE/BC)   // 32
#define NK     (KD/BK)      // 16
#define NSTEP  (NTILE*NK)   // 512 flattened k-steps

#define WS_NEEDED ((size_t)2*NCODE*KD*2 + (size_t)2*NTOK*KD*2 + (size_t)NCODE*4)

typedef float  f32x4 __attribute__((ext_vector_type(4)));
typedef __fp16 f16x8 __attribute__((ext_vector_type(8)));
typedef __fp16 f16x2 __attribute__((ext_vector_type(2)));

__device__ __forceinline__ f16x2 cvt_pk_rtz(float a, float b) {
    return __builtin_amdgcn_cvt_pkrtz(a, b);
}

// ushort-unit offset into a [rows][32] f16 tile (64B pitch), 16B-slot XOR swizzle.
__device__ __forceinline__ int lds_off(int row, int kbase) {
    int slot = kbase >> 3;            // 0..3
    int sw   = (row >> 1) & 3;
    return row * 32 + ((slot ^ sw) << 3);
}

// split v = hi + lo (f16 RTZ)
__device__ __forceinline__ void cvt_split8(f32x4 u0, f32x4 u1, f16x8& H, f16x8& L) {
    f16x2 h0 = cvt_pk_rtz(u0[0], u0[1]);
    f16x2 h1 = cvt_pk_rtz(u0[2], u0[3]);
    f16x2 h2 = cvt_pk_rtz(u1[0], u1[1]);
    f16x2 h3 = cvt_pk_rtz(u1[2], u1[3]);
    f16x2 l0 = cvt_pk_rtz(u0[0] - (float)h0[0], u0[1] - (float)h0[1]);
    f16x2 l1 = cvt_pk_rtz(u0[2] - (float)h1[0], u0[3] - (float)h1[1]);
    f16x2 l2 = cvt_pk_rtz(u1[0] - (float)h2[0], u1[1] - (float)h2[1]);
    f16x2 l3 = cvt_pk_rtz(u1[2] - (float)h3[0], u1[3] - (float)h3[1]);
    H[0]=h0[0]; H[1]=h0[1]; H[2]=h1[0]; H[3]=h1[1];
    H[4]=h2[0]; H[5]=h2[1]; H[6]=h3[0]; H[7]=h3[1];
    L[0]=l0[0]; L[1]=l0[1]; L[2]=l1[0]; L[3]=l1[1];
    L[4]=l2[0]; L[5]=l2[1]; L[6]=l3[0]; L[7]=l3[1];
}

__device__ __forceinline__ void gl_lds16(const __fp16* g, __fp16* l) {
    __builtin_amdgcn_global_load_lds((const __attribute__((address_space(1))) void*)g,
                                     (__attribute__((address_space(3))) void*)l, 16, 0, 0);
}

// ---------------- pass 1: convert + e_sq ----------------
__global__ __launch_bounds__(64)
void vq_prep(const float* __restrict__ x, const float* __restrict__ cb,
             __fp16* __restrict__ ch, __fp16* __restrict__ cl,
             __fp16* __restrict__ xh, __fp16* __restrict__ xl,
             float* __restrict__ esq)
{
    const int row = blockIdx.x;           // 0..NCODE-1 = cb, NCODE.. = x
    const int t   = threadIdx.x;          // 64 threads = 1 wave, 8 f32 each
    const bool isCb = row < NCODE;
    const size_t r = isCb ? (size_t)row : (size_t)(row - NCODE);
    const float* src = (isCb ? cb : x) + r * KD;
    __fp16* dh = (isCb ? ch : xh) + r * KD;
    __fp16* dl = (isCb ? cl : xl) + r * KD;

    const f32x4 u0 = ((const f32x4*)src)[2*t];
    const f32x4 u1 = ((const f32x4*)src)[2*t+1];
    f16x8 H, L;
    cvt_split8(u0, u1, H, L);
    ((f16x8*)dh)[t] = H;
    ((f16x8*)dl)[t] = L;

    if (isCb) {
        f32x4 sv = u0*u0 + u1*u1;
        float s = sv[0] + sv[1] + sv[2] + sv[3];
#pragma unroll
        for (int d = 1; d < 64; d <<= 1) s += __shfl_xor(s, d, 64);
        if (t == 0) esq[row] = s;
    }
}

// ---------------- pass 2: fused GEMM + argmax + gather ----------------
__global__ __launch_bounds__(256, 2)
void vq_main(const __fp16* __restrict__ ch, const __fp16* __restrict__ cl,
             const __fp16* __restrict__ xh, const __fp16* __restrict__ xl,
             const float* __restrict__ esq,
             const float* __restrict__ cb, float* __restrict__ out)
{
    __shared__ __fp16 sA[2][2][BC * 32];   // [buf][h/l][row*32]
    __shared__ __fp16 sB[2][2][BT * 32];
    __shared__ float  sMrg[4][BT][2];
    __shared__ int    sIdx[BT];

    const int tid  = threadIdx.x;
    const int lane = tid & 63;
    const int wid  = tid >> 6;      // 0..3 -> code quarter
    const int g    = lane >> 4;     // 0..3
    const int lr   = lane & 15;
    const int tok0 = blockIdx.x * BT;

    // ds_read fragment bases (swizzled)
    const int offA0 = lds_off(wid * 64 + lr, g * 8);
    const int offB0 = lds_off(lr,           g * 8);

    // global_load_lds lane offsets (ushort units), inverse-swizzled source
    const int lrow4 = lane >> 2, slot = lane & 3;
    int laneA[4];
#pragma unroll
    for (int j = 0; j < 4; ++j) {
        const int r = wid * 64 + j * 16 + lrow4;             // row in tile
        laneA[j] = r * KD + ((slot ^ ((r >> 1) & 3)) << 3);
    }
    const int rB = wid * 16 + lrow4;                          // token row in block
    const int laneB = (tok0 + rB) * KD + ((slot ^ ((rB >> 1) & 3)) << 3);

    float bv[4]; int bi[4];
#pragma unroll
    for (int nf = 0; nf < 4; ++nf) { bv[nf] = -INFINITY; bi[nf] = 0; }

    f32x4 acc[4][4];
#pragma unroll
    for (int mf = 0; mf < 4; ++mf)
#pragma unroll
        for (int nf = 0; nf < 4; ++nf)
            acc[mf][nf] = (f32x4){0.f, 0.f, 0.f, 0.f};

#define STAGE(buf, uu) do {                                                        \
        const int    tl_ = (uu) >> 4;                                              \
        const int    kk_ = ((uu) & 15) * BK;                                       \
        const size_t ab_ = (size_t)tl_ * BC * KD + kk_;                            \
        _Pragma("unroll")                                                          \
        for (int j_ = 0; j_ < 4; ++j_) {                                           \
            gl_lds16(ch + ab_ + laneA[j_], &sA[buf][0][(wid*64 + j_*16) * 32]);    \
            gl_lds16(cl + ab_ + laneA[j_], &sA[buf][1][(wid*64 + j_*16) * 32]);    \
        }                                                                          \
        gl_lds16(xh + kk_ + laneB, &sB[buf][0][(wid*16) * 32]);                    \
        gl_lds16(xl + kk_ + laneB, &sB[buf][1][(wid*16) * 32]);                    \
    } while (0)

    // prologue: stage step 0 into buf 0
    STAGE(0, 0);
    __syncthreads();

    int cur = 0;
    for (int u = 0; u < NSTEP; ++u) {
        // stage next step into the other buffer (loads stay in flight under compute)
        if (u != NSTEP - 1) STAGE(cur ^ 1, u + 1);

        // fragments of current buffer
        f16x8 bh[4], bl[4];
#pragma unroll
        for (int nf = 0; nf < 4; ++nf) {
            bh[nf] = *(const f16x8*)&sB[cur][0][offB0 + nf * 512];
            bl[nf] = *(const f16x8*)&sB[cur][1][offB0 + nf * 512];
        }
#pragma unroll
        for (int mf = 0; mf < 4; ++mf) {
            f16x8 ah = *(const f16x8*)&sA[cur][0][offA0 + mf * 512];
            f16x8 al = *(const f16x8*)&sA[cur][1][offA0 + mf * 512];
#pragma unroll
            for (int nf = 0; nf < 4; ++nf)
                acc[mf][nf] = __builtin_amdgcn_mfma_f32_16x16x32_f16(ah, bh[nf], acc[mf][nf], 0, 0, 0);
#pragma unroll
            for (int nf = 0; nf < 4; ++nf)
                acc[mf][nf] = __builtin_amdgcn_mfma_f32_16x16x32_f16(ah, bl[nf], acc[mf][nf], 0, 0, 0);
#pragma unroll
            for (int nf = 0; nf < 4; ++nf)
                acc[mf][nf] = __builtin_amdgcn_mfma_f32_16x16x32_f16(al, bh[nf], acc[mf][nf], 0, 0, 0);
        }

        // per-tile epilogue: score = e_sq - 2*(x.c); running argmax; reset acc
        if ((u & 15) == 15) {
            const int tile = u >> 4;
            const int codeTileBase = tile * BC;
#pragma unroll
            for (int mf = 0; mf < 4; ++mf) {
                const int cl_ = wid * 64 + mf * 16 + g * 4;
                const f32x4 es = *(const f32x4*)&esq[codeTileBase + cl_];
                const int cbase = codeTileBase + cl_;
#pragma unroll
                for (int r = 0; r < 4; ++r) {
#pragma unroll
                    for (int nf = 0; nf < 4; ++nf) {
                        const float s = fmaf(-2.0f, acc[mf][nf][r], es[r]);
                        if (s > bv[nf]) { bv[nf] = s; bi[nf] = cbase + r; }
                        acc[mf][nf][r] = 0.f;
                    }
                }
            }
        }

        __syncthreads();   // vmcnt(0)+lgkmcnt(0)+barrier: staged next-buf complete, reads done
        cur ^= 1;
    }
#undef STAGE

    // ---- cross-lane reduce over the 4 row-groups ----
#pragma unroll
    for (int nf = 0; nf < 4; ++nf) {
#pragma unroll
        for (int d = 16; d <= 32; d <<= 1) {
            const float ov = __shfl_xor(bv[nf], d, 64);
            const int   oi = __shfl_xor(bi[nf], d, 64);
            if (ov > bv[nf] || (ov == bv[nf] && oi < bi[nf])) { bv[nf] = ov; bi[nf] = oi; }
        }
    }
    if (g == 0) {
#pragma unroll
        for (int nf = 0; nf < 4; ++nf) {
            const int tl = nf * 16 + lr;
            sMrg[wid][tl][0] = bv[nf];
            sMrg[wid][tl][1] = __int_as_float(bi[nf]);
        }
    }
    __syncthreads();

    if (tid < BT) {
        float v = sMrg[0][tid][0];
        int   idx = __float_as_int(sMrg[0][tid][1]);
#pragma unroll
        for (int w = 1; w < 4; ++w) {
            const float vw = sMrg[w][tid][0];
            const int   iw = __float_as_int(sMrg[w][tid][1]);
            if (vw > v || (vw == v && iw < idx)) { v = vw; idx = iw; }
        }
        sIdx[tid] = idx;
    }
    __syncthreads();

    // gather: exact f32 copy of winning codebook rows
    const f32x4* cb4  = (const f32x4*)cb;
    f32x4*       out4 = (f32x4*)out;
    for (int i = tid; i < BT * (KD / 4); i += 256) {
        const int r = i >> 7;
        const int c = i & 127;
        out4[(size_t)(tok0 + r) * 128 + c] = cb4[(size_t)sIdx[r] * 128 + c];
    }
}

// ---------------- fallback (R5 kernel, in-loop conversion) ----------------
__global__ __launch_bounds__(256, 2)
void vq_fallback(const float* __restrict__ x,
                 const float* __restrict__ cb,
                 float* __restrict__ out)
{
    __shared__ __fp16 sAh[BC * 32];
    __shared__ __fp16 sAl[BC * 32];
    __shared__ __fp16 sBh[BT * 32];
    __shared__ __fp16 sBl[BT * 32];
    __shared__ float  sEsq[BC];
    __shared__ float  sMrg[4][BT][2];
    __shared__ int    sIdx[BT];

    const int tid  = threadIdx.x;
    const int lane = tid & 63;
    const int wid  = tid >> 6;
    const int g    = lane >> 4;
    const int lr   = lane & 15;
    const int tok0 = blockIdx.x * BT;

    const int offA0 = lds_off(wid * 64 + lr, g * 8);
    const int offB0 = lds_off(lr,           g * 8);

    const float* aSrc = cb + (size_t)tid * KD;
    const int brow = tid >> 2, bq = tid & 3;
    const float* bSrc = x + (size_t)(tok0 + brow) * KD + bq * 8;

    const int awBase = tid * 32,  swA = (tid >> 1) & 3;
    const int bwOff  = brow * 32 + (((bq ^ ((brow >> 1) & 3))) << 3);

    f32x4 ar[8], br[2];
    {
        const f32x4* ap = (const f32x4*)aSrc;
#pragma unroll
        for (int j = 0; j < 8; ++j) ar[j] = ap[j];
        const f32x4* bp = (const f32x4*)bSrc;
        br[0] = bp[0]; br[1] = bp[1];
    }

    float bv[4]; int bi[4];
#pragma unroll
    for (int nf = 0; nf < 4; ++nf) { bv[nf] = -INFINITY; bi[nf] = 0; }

    f32x4 acc[4][4];

    for (int nt = 0; nt < NTILE; ++nt) {
#pragma unroll
        for (int mf = 0; mf < 4; ++mf)
#pragma unroll
            for (int nf = 0; nf < 4; ++nf)
                acc[mf][nf] = (f32x4){0.f, 0.f, 0.f, 0.f};

        f32x4 esqv = {0.f, 0.f, 0.f, 0.f};

        for (int ks = 0; ks < NK; ++ks) {
#pragma unroll
            for (int s = 0; s < 4; ++s) {
                f32x4 u0 = ar[2*s], u1 = ar[2*s+1];
                esqv += u0 * u0;
                esqv += u1 * u1;
                f16x8 H, L;
                cvt_split8(u0, u1, H, L);
                const int aw = awBase + ((s ^ swA) << 3);
                *(f16x8*)&sAh[aw] = H;
                *(f16x8*)&sAl[aw] = L;
            }
            {
                f16x8 H, L;
                cvt_split8(br[0], br[1], H, L);
                *(f16x8*)&sBh[bwOff] = H;
                *(f16x8*)&sBl[bwOff] = L;
            }
            if (ks == NK - 1) sEsq[tid] = esqv[0] + esqv[1] + esqv[2] + esqv[3];

            if (!(nt == NTILE - 1 && ks == NK - 1)) {
                const int nnt = (ks == NK - 1) ? nt + 1 : nt;
                const int nks = (ks == NK - 1) ? 0 : ks + 1;
                const f32x4* ap = (const f32x4*)(aSrc + (size_t)nnt * BC * KD + nks * BK);
#pragma unroll
                for (int j = 0; j < 8; ++j) ar[j] = ap[j];
                const f32x4* bp = (const f32x4*)(bSrc + nks * BK);
                br[0] = bp[0]; br[1] = bp[1];
            }

            __syncthreads();

            f16x8 bh[4], bl[4];
#pragma unroll
            for (int nf = 0; nf < 4; ++nf) {
                bh[nf] = *(const f16x8*)&sBh[offB0 + nf * 512];
                bl[nf] = *(const f16x8*)&sBl[offB0 + nf * 512];
            }
#pragma unroll
            for (int mf = 0; mf < 4; ++mf) {
                f16x8 ah = *(const f16x8*)&sAh[offA0 + mf * 512];
                f16x8 al = *(const f16x8*)&sAl[offA0 + mf * 512];
#pragma unroll
                for (int nf = 0; nf < 4; ++nf)
                    acc[mf][nf] = __builtin_amdgcn_mfma_f32_16x16x32_f16(ah, bh[nf], acc[mf][nf], 0, 0, 0);
#pragma unroll
                for (int nf = 0; nf < 4; ++nf)
                    acc[mf][nf] = __builtin_amdgcn_mfma_f32_16x16x32_f16(ah, bl[nf], acc[mf][nf], 0, 0, 0);
#pragma unroll
                for (int nf = 0; nf < 4; ++nf)
                    acc[mf][nf] = __builtin_amdgcn_mfma_f32_16x16x32_f16(al, bh[nf], acc[mf][nf], 0, 0, 0);
            }
            __syncthreads();
        }

        const int codeTileBase = nt * BC;
#pragma unroll
        for (int mf = 0; mf < 4; ++mf) {
            const int cl = wid * 64 + mf * 16 + g * 4;
            const f32x4 es = *(const f32x4*)&sEsq[cl];
            const int cbase = codeTileBase + cl;
#pragma unroll
            for (int r = 0; r < 4; ++r) {
#pragma unroll
                for (int nf = 0; nf < 4; ++nf) {
                    const float s = fmaf(-2.0f, acc[mf][nf][r], es[r]);
                    if (s > bv[nf]) { bv[nf] = s; bi[nf] = cbase + r; }
                }
            }
        }
    }

#pragma unroll
    for (int nf = 0; nf < 4; ++nf) {
#pragma unroll
        for (int d = 16; d <= 32; d <<= 1) {
            const float ov = __shfl_xor(bv[nf], d, 64);
            const int   oi = __shfl_xor(bi[nf], d, 64);
            if (ov > bv[nf] || (ov == bv[nf] && oi < bi[nf])) { bv[nf] = ov; bi[nf] = oi; }
        }
    }
    if (g == 0) {
#pragma unroll
        for (int nf = 0; nf < 4; ++nf) {
            const int tl = nf * 16 + lr;
            sMrg[wid][tl][0] = bv[nf];
            sMrg[wid][tl][1] = __int_as_float(bi[nf]);
        }
    }
    __syncthreads();

    if (tid < BT) {
        float v = sMrg[0][tid][0];
        int   idx = __float_as_int(sMrg[0][tid][1]);
#pragma unroll
        for (int w = 1; w < 4; ++w) {
            const float vw = sMrg[w][tid][0];
            const int   iw = __float_as_int(sMrg[w][tid][1]);
            if (vw > v || (vw == v && iw < idx)) { v = vw; idx = iw; }
        }
        sIdx[tid] = idx;
    }
    __syncthreads();

    const f32x4* cb4  = (const f32x4*)cb;
    f32x4*       out4 = (f32x4*)out;
    for (int i = tid; i < BT * (KD / 4); i += 256) {
        const int r = i >> 7;
        const int c = i & 127;
        out4[(size_t)(tok0 + r) * 128 + c] = cb4[(size_t)sIdx[r] * 128 + c];
    }
}

extern "C" void kernel_launch(void* const* d_in, const int* in_sizes, int n_in,
                              void* d_out, int out_size, void* d_ws, size_t ws_size,
                              hipStream_t stream) {
    const float* x   = (const float*)d_in[0];   // [32768, 512] f32
    const float* cb  = (const float*)d_in[1];   // [8192, 512] f32
    float*       out = (float*)d_out;           // [32768, 512] f32
    (void)in_sizes; (void)n_in; (void)out_size;

    if (ws_size >= WS_NEEDED) {
        __fp16* ch = (__fp16*)d_ws;
        __fp16* cl = ch + (size_t)NCODE * KD;
        __fp16* xh = cl + (size_t)NCODE * KD;
        __fp16* xl = xh + (size_t)NTOK * KD;
        float*  esq = (float*)(xl + (size_t)NTOK * KD);

        vq_prep<<<dim3(NCODE + NTOK), dim3(64), 0, stream>>>(x, cb, ch, cl, xh, xl, esq);
        vq_main<<<dim3(NTOK / BT), dim3(256), 0, stream>>>(ch, cl, xh, xl, esq, cb, out);
    } else {
        vq_fallback<<<dim3(NTOK / BT), dim3(256), 0, stream>>>(x, cb, out);
    }
}

// Round 8
// 615.468 us; speedup vs baseline: 2.4245x; 2.4245x over previous
//
#include <hip/hip_runtime.h>
#include <math.h>

// VQ nearest-code: out[t] = codebook[argmax_k(e_sq[k] - 2*x_t.c_k)]
// R7: hi-only f16 MFMA screening GEMM + margin candidate capture + exact f32 rescore.
//     prep: cb/x -> f16 hi + e_sq in d_ws. main: dbuf global_load_lds staging,
//     per-token shared running max, capture codes within MARGIN of max, tail rescore.

#define NTOK   32768
#define NCODE  8192
#define KD     512
#define BT     64
#define BC     256
#define BK     32
#define NTILE  (NCODE/BC)   // 32
#define NK     (KD/BK)      // 16
#define NSTEP  (NTILE*NK)   // 512
#define CAP    32
#define MARGIN 0.5f

#define WS_NEEDED ((size_t)NCODE*KD*2 + (size_t)NTOK*KD*2 + (size_t)NCODE*4)

typedef float  f32x4 __attribute__((ext_vector_type(4)));
typedef __fp16 f16x8 __attribute__((ext_vector_type(8)));
typedef __fp16 f16x2 __attribute__((ext_vector_type(2)));

__device__ __forceinline__ f16x2 cvt_pk_rtz(float a, float b) {
    return __builtin_amdgcn_cvt_pkrtz(a, b);
}

// ordered-uint encoding of float (monotone)
__device__ __forceinline__ unsigned ordf(float f) {
    unsigned u = __float_as_uint(f);
    return ((int)u >= 0) ? (u | 0x80000000u) : ~u;
}
__device__ __forceinline__ float iordf(unsigned e) {
    unsigned b = (e & 0x80000000u) ? (e & 0x7FFFFFFFu) : ~e;
    return __uint_as_float(b);
}

// ushort-unit offset into a [rows][32] f16 tile (64B pitch), 16B-slot XOR swizzle.
__device__ __forceinline__ int lds_off(int row, int kbase) {
    int slot = kbase >> 3;
    int sw   = (row >> 1) & 3;
    return row * 32 + ((slot ^ sw) << 3);
}

__device__ __forceinline__ void gl_lds16(const __fp16* g, __fp16* l) {
    __builtin_amdgcn_global_load_lds((const __attribute__((address_space(1))) void*)g,
                                     (__attribute__((address_space(3))) void*)l, 16, 0, 0);
}

// ---------------- pass 1: f32 -> f16 hi + e_sq ----------------
__global__ __launch_bounds__(64)
void vq_prep(const float* __restrict__ x, const float* __restrict__ cb,
             __fp16* __restrict__ ch, __fp16* __restrict__ xh,
             float* __restrict__ esq)
{
    const int row = blockIdx.x;
    const int t   = threadIdx.x;
    const bool isCb = row < NCODE;
    const size_t r = isCb ? (size_t)row : (size_t)(row - NCODE);
    const float* src = (isCb ? cb : x) + r * KD;
    __fp16* dh = (isCb ? ch : xh) + r * KD;

    const f32x4 u0 = ((const f32x4*)src)[2*t];
    const f32x4 u1 = ((const f32x4*)src)[2*t+1];
    f16x2 h0 = cvt_pk_rtz(u0[0], u0[1]);
    f16x2 h1 = cvt_pk_rtz(u0[2], u0[3]);
    f16x2 h2 = cvt_pk_rtz(u1[0], u1[1]);
    f16x2 h3 = cvt_pk_rtz(u1[2], u1[3]);
    f16x8 H;
    H[0]=h0[0]; H[1]=h0[1]; H[2]=h1[0]; H[3]=h1[1];
    H[4]=h2[0]; H[5]=h2[1]; H[6]=h3[0]; H[7]=h3[1];
    ((f16x8*)dh)[t] = H;

    if (isCb) {
        f32x4 sv = u0*u0 + u1*u1;
        float s = sv[0] + sv[1] + sv[2] + sv[3];
#pragma unroll
        for (int d = 1; d < 64; d <<= 1) s += __shfl_xor(s, d, 64);
        if (t == 0) esq[row] = s;
    }
}

// ---------------- pass 2: screening GEMM + capture + rescore + gather ----------------
__global__ __launch_bounds__(256, 3)
void vq_main(const __fp16* __restrict__ ch, const __fp16* __restrict__ xh,
             const float* __restrict__ esq,
             const float* __restrict__ x, const float* __restrict__ cb,
             float* __restrict__ out)
{
    __shared__ __fp16 sA[2][BC * 32];
    __shared__ __fp16 sB[2][BT * 32];
    __shared__ unsigned smax[BT];
    __shared__ int cnt[BT];
    __shared__ int cand[BT][CAP];
    __shared__ unsigned long long best[BT];

    const int tid  = threadIdx.x;
    const int lane = tid & 63;
    const int wid  = tid >> 6;      // code quarter
    const int g    = lane >> 4;
    const int lr   = lane & 15;
    const int tok0 = blockIdx.x * BT;

    if (tid < BT) { smax[tid] = 0u; cnt[tid] = 0; best[tid] = 0ull; }

    const int offA0 = lds_off(wid * 64 + lr, g * 8);
    const int offB0 = lds_off(lr,           g * 8);

    // global_load_lds lane offsets (ushort units), inverse-swizzled source
    const int lrow4 = lane >> 2, slot = lane & 3;
    int laneA[4];
#pragma unroll
    for (int j = 0; j < 4; ++j) {
        const int r = wid * 64 + j * 16 + lrow4;
        laneA[j] = r * KD + ((slot ^ ((r >> 1) & 3)) << 3);
    }
    const int rB = wid * 16 + lrow4;
    const int laneB = (tok0 + rB) * KD + ((slot ^ ((rB >> 1) & 3)) << 3);

    f32x4 acc[4][4];
#pragma unroll
    for (int mf = 0; mf < 4; ++mf)
#pragma unroll
        for (int nf = 0; nf < 4; ++nf)
            acc[mf][nf] = (f32x4){0.f, 0.f, 0.f, 0.f};

#define STAGE(buf, uu) do {                                                   \
        const int    tl_ = (uu) >> 4;                                         \
        const int    kk_ = ((uu) & 15) * BK;                                  \
        const size_t ab_ = (size_t)tl_ * BC * KD + kk_;                       \
        _Pragma("unroll")                                                     \
        for (int j_ = 0; j_ < 4; ++j_)                                        \
            gl_lds16(ch + ab_ + laneA[j_], &sA[buf][(wid*64 + j_*16) * 32]);  \
        gl_lds16(xh + kk_ + laneB, &sB[buf][(wid*16) * 32]);                  \
    } while (0)

    STAGE(0, 0);
    __syncthreads();

    int cur = 0;
    for (int u = 0; u < NSTEP; ++u) {
        if (u != NSTEP - 1) STAGE(cur ^ 1, u + 1);

        f16x8 bh[4];
#pragma unroll
        for (int nf = 0; nf < 4; ++nf)
            bh[nf] = *(const f16x8*)&sB[cur][offB0 + nf * 512];
#pragma unroll
        for (int mf = 0; mf < 4; ++mf) {
            f16x8 ah = *(const f16x8*)&sA[cur][offA0 + mf * 512];
#pragma unroll
            for (int nf = 0; nf < 4; ++nf)
                acc[mf][nf] = __builtin_amdgcn_mfma_f32_16x16x32_f16(ah, bh[nf], acc[mf][nf], 0, 0, 0);
        }

        if ((u & 15) == 15) {
            const int codeTileBase = (u >> 4) * BC;
            // phase 1: scores into acc; per-token shared max update
            float tmax[4];
#pragma unroll
            for (int nf = 0; nf < 4; ++nf) tmax[nf] = -INFINITY;
#pragma unroll
            for (int mf = 0; mf < 4; ++mf) {
                const int cl_ = codeTileBase + wid * 64 + mf * 16 + g * 4;
                const f32x4 es = *(const f32x4*)&esq[cl_];
#pragma unroll
                for (int r = 0; r < 4; ++r)
#pragma unroll
                    for (int nf = 0; nf < 4; ++nf) {
                        const float s = fmaf(-2.0f, acc[mf][nf][r], es[r]);
                        acc[mf][nf][r] = s;
                        tmax[nf] = fmaxf(tmax[nf], s);
                    }
            }
#pragma unroll
            for (int nf = 0; nf < 4; ++nf) {
                tmax[nf] = fmaxf(tmax[nf], __shfl_xor(tmax[nf], 16, 64));
                tmax[nf] = fmaxf(tmax[nf], __shfl_xor(tmax[nf], 32, 64));
            }
            if (g == 0) {
#pragma unroll
                for (int nf = 0; nf < 4; ++nf)
                    atomicMax(&smax[nf * 16 + lr], ordf(tmax[nf]));
            }
            __syncthreads();
            // phase 2: capture candidates within MARGIN of updated shared max
            float thr[4];
#pragma unroll
            for (int nf = 0; nf < 4; ++nf) thr[nf] = iordf(smax[nf * 16 + lr]) - MARGIN;
#pragma unroll
            for (int mf = 0; mf < 4; ++mf) {
                const int cbase = codeTileBase + wid * 64 + mf * 16 + g * 4;
#pragma unroll
                for (int r = 0; r < 4; ++r)
#pragma unroll
                    for (int nf = 0; nf < 4; ++nf) {
                        if (acc[mf][nf][r] >= thr[nf]) {
                            const int tok = nf * 16 + lr;
                            const int p = atomicAdd(&cnt[tok], 1);
                            if (p < CAP) cand[tok][p] = cbase + r;
                        }
                        acc[mf][nf][r] = 0.f;
                    }
            }
        }

        __syncthreads();
        cur ^= 1;
    }
#undef STAGE

    // ---- exact f32 rescore of candidates (wave per token, round-robin) ----
    for (int t = wid; t < BT; t += 4) {
        const int n = cnt[t];
        const float* xrow = x + (size_t)(tok0 + t) * KD;
        const f32x4 xr0 = ((const f32x4*)xrow)[lane * 2];
        const f32x4 xr1 = ((const f32x4*)xrow)[lane * 2 + 1];
        const int m = (n > CAP) ? NCODE : n;   // overflow -> certified full scan
        for (int j = 0; j < m; ++j) {
            const int k = (n > CAP) ? j : cand[t][j];
            const f32x4* crow = (const f32x4*)(cb + (size_t)k * KD);
            const f32x4 c0 = crow[lane * 2];
            const f32x4 c1 = crow[lane * 2 + 1];
            const f32x4 pv = xr0 * c0 + xr1 * c1;
            float d = pv[0] + pv[1] + pv[2] + pv[3];
#pragma unroll
            for (int dd = 1; dd < 64; dd <<= 1) d += __shfl_xor(d, dd, 64);
            const float s = esq[k] - 2.0f * d;
            if (lane == 0) {
                const unsigned long long enc =
                    ((unsigned long long)ordf(s) << 32) | (unsigned)(~k);
                atomicMax(&best[t], enc);
            }
        }
    }
    __syncthreads();

    // ---- gather: out[token] = codebook[best_idx] (exact f32 copy) ----
    const f32x4* cb4  = (const f32x4*)cb;
    f32x4*       out4 = (f32x4*)out;
    for (int i = tid; i < BT * (KD / 4); i += 256) {
        const int r = i >> 7;
        const int c = i & 127;
        const unsigned k = ~(unsigned)(best[r] & 0xFFFFFFFFull);
        out4[(size_t)(tok0 + r) * 128 + c] = cb4[(size_t)k * 128 + c];
    }
}

// ---------------- fallback (R5 kernel: exact 3-product, no workspace) ----------------
__device__ __forceinline__ void cvt_split8(f32x4 u0, f32x4 u1, f16x8& H, f16x8& L) {
    f16x2 h0 = cvt_pk_rtz(u0[0], u0[1]);
    f16x2 h1 = cvt_pk_rtz(u0[2], u0[3]);
    f16x2 h2 = cvt_pk_rtz(u1[0], u1[1]);
    f16x2 h3 = cvt_pk_rtz(u1[2], u1[3]);
    f16x2 l0 = cvt_pk_rtz(u0[0] - (float)h0[0], u0[1] - (float)h0[1]);
    f16x2 l1 = cvt_pk_rtz(u0[2] - (float)h1[0], u0[3] - (float)h1[1]);
    f16x2 l2 = cvt_pk_rtz(u1[0] - (float)h2[0], u1[1] - (float)h2[1]);
    f16x2 l3 = cvt_pk_rtz(u1[2] - (float)h3[0], u1[3] - (float)h3[1]);
    H[0]=h0[0]; H[1]=h0[1]; H[2]=h1[0]; H[3]=h1[1];
    H[4]=h2[0]; H[5]=h2[1]; H[6]=h3[0]; H[7]=h3[1];
    L[0]=l0[0]; L[1]=l0[1]; L[2]=l1[0]; L[3]=l1[1];
    L[4]=l2[0]; L[5]=l2[1]; L[6]=l3[0]; L[7]=l3[1];
}

__global__ __launch_bounds__(256, 2)
void vq_fallback(const float* __restrict__ x,
                 const float* __restrict__ cb,
                 float* __restrict__ out)
{
    __shared__ __fp16 sAh[BC * 32];
    __shared__ __fp16 sAl[BC * 32];
    __shared__ __fp16 sBh[BT * 32];
    __shared__ __fp16 sBl[BT * 32];
    __shared__ float  sEsq[BC];
    __shared__ float  sMrg[4][BT][2];
    __shared__ int    sIdx[BT];

    const int tid  = threadIdx.x;
    const int lane = tid & 63;
    const int wid  = tid >> 6;
    const int g    = lane >> 4;
    const int lr   = lane & 15;
    const int tok0 = blockIdx.x * BT;

    const int offA0 = lds_off(wid * 64 + lr, g * 8);
    const int offB0 = lds_off(lr,           g * 8);

    const float* aSrc = cb + (size_t)tid * KD;
    const int brow = tid >> 2, bq = tid & 3;
    const float* bSrc = x + (size_t)(tok0 + brow) * KD + bq * 8;

    const int awBase = tid * 32,  swA = (tid >> 1) & 3;
    const int bwOff  = brow * 32 + (((bq ^ ((brow >> 1) & 3))) << 3);

    f32x4 ar[8], br[2];
    {
        const f32x4* ap = (const f32x4*)aSrc;
#pragma unroll
        for (int j = 0; j < 8; ++j) ar[j] = ap[j];
        const f32x4* bp = (const f32x4*)bSrc;
        br[0] = bp[0]; br[1] = bp[1];
    }

    float bv[4]; int bi[4];
#pragma unroll
    for (int nf = 0; nf < 4; ++nf) { bv[nf] = -INFINITY; bi[nf] = 0; }

    f32x4 acc[4][4];

    for (int nt = 0; nt < NTILE; ++nt) {
#pragma unroll
        for (int mf = 0; mf < 4; ++mf)
#pragma unroll
            for (int nf = 0; nf < 4; ++nf)
                acc[mf][nf] = (f32x4){0.f, 0.f, 0.f, 0.f};

        f32x4 esqv = {0.f, 0.f, 0.f, 0.f};

        for (int ks = 0; ks < NK; ++ks) {
#pragma unroll
            for (int s = 0; s < 4; ++s) {
                f32x4 u0 = ar[2*s], u1 = ar[2*s+1];
                esqv += u0 * u0;
                esqv += u1 * u1;
                f16x8 H, L;
                cvt_split8(u0, u1, H, L);
                const int aw = awBase + ((s ^ swA) << 3);
                *(f16x8*)&sAh[aw] = H;
                *(f16x8*)&sAl[aw] = L;
            }
            {
                f16x8 H, L;
                cvt_split8(br[0], br[1], H, L);
                *(f16x8*)&sBh[bwOff] = H;
                *(f16x8*)&sBl[bwOff] = L;
            }
            if (ks == NK - 1) sEsq[tid] = esqv[0] + esqv[1] + esqv[2] + esqv[3];

            if (!(nt == NTILE - 1 && ks == NK - 1)) {
                const int nnt = (ks == NK - 1) ? nt + 1 : nt;
                const int nks = (ks == NK - 1) ? 0 : ks + 1;
                const f32x4* ap = (const f32x4*)(aSrc + (size_t)nnt * BC * KD + nks * BK);
#pragma unroll
                for (int j = 0; j < 8; ++j) ar[j] = ap[j];
                const f32x4* bp = (const f32x4*)(bSrc + nks * BK);
                br[0] = bp[0]; br[1] = bp[1];
            }

            __syncthreads();

            f16x8 bh[4], bl[4];
#pragma unroll
            for (int nf = 0; nf < 4; ++nf) {
                bh[nf] = *(const f16x8*)&sBh[offB0 + nf * 512];
                bl[nf] = *(const f16x8*)&sBl[offB0 + nf * 512];
            }
#pragma unroll
            for (int mf = 0; mf < 4; ++mf) {
                f16x8 ah = *(const f16x8*)&sAh[offA0 + mf * 512];
                f16x8 al = *(const f16x8*)&sAl[offA0 + mf * 512];
#pragma unroll
                for (int nf = 0; nf < 4; ++nf)
                    acc[mf][nf] = __builtin_amdgcn_mfma_f32_16x16x32_f16(ah, bh[nf], acc[mf][nf], 0, 0, 0);
#pragma unroll
                for (int nf = 0; nf < 4; ++nf)
                    acc[mf][nf] = __builtin_amdgcn_mfma_f32_16x16x32_f16(ah, bl[nf], acc[mf][nf], 0, 0, 0);
#pragma unroll
                for (int nf = 0; nf < 4; ++nf)
                    acc[mf][nf] = __builtin_amdgcn_mfma_f32_16x16x32_f16(al, bh[nf], acc[mf][nf], 0, 0, 0);
            }
            __syncthreads();
        }

        const int codeTileBase = nt * BC;
#pragma unroll
        for (int mf = 0; mf < 4; ++mf) {
            const int cl = wid * 64 + mf * 16 + g * 4;
            const f32x4 es = *(const f32x4*)&sEsq[cl];
            const int cbase = codeTileBase + cl;
#pragma unroll
            for (int r = 0; r < 4; ++r) {
#pragma unroll
                for (int nf = 0; nf < 4; ++nf) {
                    const float s = fmaf(-2.0f, acc[mf][nf][r], es[r]);
                    if (s > bv[nf]) { bv[nf] = s; bi[nf] = cbase + r; }
                }
            }
        }
    }

#pragma unroll
    for (int nf = 0; nf < 4; ++nf) {
#pragma unroll
        for (int d = 16; d <= 32; d <<= 1) {
            const float ov = __shfl_xor(bv[nf], d, 64);
            const int   oi = __shfl_xor(bi[nf], d, 64);
            if (ov > bv[nf] || (ov == bv[nf] && oi < bi[nf])) { bv[nf] = ov; bi[nf] = oi; }
        }
    }
    if (g == 0) {
#pragma unroll
        for (int nf = 0; nf < 4; ++nf) {
            const int tl = nf * 16 + lr;
            sMrg[wid][tl][0] = bv[nf];
            sMrg[wid][tl][1] = __int_as_float(bi[nf]);
        }
    }
    __syncthreads();

    if (tid < BT) {
        float v = sMrg[0][tid][0];
        int   idx = __float_as_int(sMrg[0][tid][1]);
#pragma unroll
        for (int w = 1; w < 4; ++w) {
            const float vw = sMrg[w][tid][0];
            const int   iw = __float_as_int(sMrg[w][tid][1]);
            if (vw > v || (vw == v && iw < idx)) { v = vw; idx = iw; }
        }
        sIdx[tid] = idx;
    }
    __syncthreads();

    const f32x4* cb4  = (const f32x4*)cb;
    f32x4*       out4 = (f32x4*)out;
    for (int i = tid; i < BT * (KD / 4); i += 256) {
        const int r = i >> 7;
        const int c = i & 127;
        out4[(size_t)(tok0 + r) * 128 + c] = cb4[(size_t)sIdx[r] * 128 + c];
    }
}

extern "C" void kernel_launch(void* const* d_in, const int* in_sizes, int n_in,
                              void* d_out, int out_size, void* d_ws, size_t ws_size,
                              hipStream_t stream) {
    const float* x   = (const float*)d_in[0];   // [32768, 512] f32
    const float* cb  = (const float*)d_in[1];   // [8192, 512] f32
    float*       out = (float*)d_out;           // [32768, 512] f32
    (void)in_sizes; (void)n_in; (void)out_size;

    if (ws_size >= WS_NEEDED) {
        __fp16* ch = (__fp16*)d_ws;
        __fp16* xh = ch + (size_t)NCODE * KD;
        float*  esq = (float*)(xh + (size_t)NTOK * KD);

        vq_prep<<<dim3(NCODE + NTOK), dim3(64), 0, stream>>>(x, cb, ch, xh, esq);
        vq_main<<<dim3(NTOK / BT), dim3(256), 0, stream>>>(ch, xh, esq, x, cb, out);
    } else {
        vq_fallback<<<dim3(NTOK / BT), dim3(256), 0, stream>>>(x, cb, out);
    }
}